// Round 2
// baseline (277.804 us; speedup 1.0000x reference)
//
#include <hip/hip_runtime.h>

#define DD 4096
#define SS 8192

// One wave (64 lanes) per output logit. Each lane reads 16 float4 (256 B) of
// the 16 KiB row -> 16 independent loads in flight; wave-only shuffle reduce.
// 4 waves per 256-thread block => grid = 2*SS/4 = 4096 blocks.
__global__ __launch_bounds__(256) void gemv_kernel(
    const float* __restrict__ G1, const float* __restrict__ G2,
    const float* __restrict__ wp1, const float* __restrict__ wp2,
    float* __restrict__ logits)
{
    const int wid  = threadIdx.x >> 6;          // wave within block, 0..3
    const int lane = threadIdx.x & 63;          // 0..63
    const int rg   = blockIdx.x * 4 + wid;      // global row id, 0 .. 2*SS-1

    const float* G;
    const float* w;
    int row;
    if (rg < SS) { G = G1; w = wp1; row = rg; }
    else         { G = G2; w = wp2; row = rg - SS; }

    const float4* __restrict__ Grow = reinterpret_cast<const float4*>(G + (size_t)row * DD);
    const float4* __restrict__ W4   = reinterpret_cast<const float4*>(w);

    float acc = 0.f;
    #pragma unroll
    for (int i = 0; i < DD / 4 / 64; ++i) {     // 16 iterations, fully unrolled
        float4 g  = Grow[i * 64 + lane];
        float4 ww = W4[i * 64 + lane];
        acc = fmaf(g.x, ww.x, acc);
        acc = fmaf(g.y, ww.y, acc);
        acc = fmaf(g.z, ww.z, acc);
        acc = fmaf(g.w, ww.w, acc);
    }

    // 64-lane butterfly reduce
    #pragma unroll
    for (int off = 32; off > 0; off >>= 1)
        acc += __shfl_xor(acc, off, 64);

    if (lane == 0)
        logits[rg] = acc;
}

// One block per softmax row (2 blocks x 1024 threads, 8 elements/thread).
__global__ __launch_bounds__(1024) void softmax_kernel(
    const float* __restrict__ logits, float* __restrict__ out)
{
    const int r = blockIdx.x;   // 0 or 1
    const int t = threadIdx.x;  // 0 .. 1023
    const float* __restrict__ x = logits + (size_t)r * SS;

    float v[8];
    float m = -INFINITY;
    #pragma unroll
    for (int i = 0; i < 8; ++i) {
        v[i] = x[t + i * 1024];
        m = fmaxf(m, v[i]);
    }

    __shared__ float red[16];

    // block max-reduce: wave(64) shuffle, then cross-wave (16 waves) via LDS
    #pragma unroll
    for (int off = 32; off > 0; off >>= 1)
        m = fmaxf(m, __shfl_xor(m, off, 64));
    if ((t & 63) == 0) red[t >> 6] = m;
    __syncthreads();
    if (t < 64) {
        float mm = (t < 16) ? red[t] : -INFINITY;
        #pragma unroll
        for (int off = 8; off > 0; off >>= 1)
            mm = fmaxf(mm, __shfl_xor(mm, off, 64));
        if (t == 0) red[0] = mm;
    }
    __syncthreads();
    m = red[0];
    __syncthreads();   // red[] reused below

    float s = 0.f;
    #pragma unroll
    for (int i = 0; i < 8; ++i) {
        v[i] = expf(v[i] - m);
        s += v[i];
    }
    #pragma unroll
    for (int off = 32; off > 0; off >>= 1)
        s += __shfl_xor(s, off, 64);
    if ((t & 63) == 0) red[t >> 6] = s;
    __syncthreads();
    if (t < 64) {
        float ss = (t < 16) ? red[t] : 0.f;
        #pragma unroll
        for (int off = 8; off > 0; off >>= 1)
            ss += __shfl_xor(ss, off, 64);
        if (t == 0) red[0] = ss;
    }
    __syncthreads();
    const float inv = 1.0f / red[0];

    #pragma unroll
    for (int i = 0; i < 8; ++i)
        out[(size_t)r * SS + t + i * 1024] = v[i] * inv;
}

extern "C" void kernel_launch(void* const* d_in, const int* in_sizes, int n_in,
                              void* d_out, int out_size, void* d_ws, size_t ws_size,
                              hipStream_t stream) {
    const float* G1  = (const float*)d_in[0];
    const float* G2  = (const float*)d_in[1];
    const float* wp1 = (const float*)d_in[2];
    const float* wp2 = (const float*)d_in[3];
    float* out    = (float*)d_out;
    float* logits = (float*)d_ws;   // 2*SS floats = 64 KiB scratch

    gemv_kernel<<<(2 * SS) / 4, 256, 0, stream>>>(G1, G2, wp1, wp2, logits);
    softmax_kernel<<<2, 1024, 0, stream>>>(logits, out);
}